// Round 6
// baseline (178.526 us; speedup 1.0000x reference)
//
#include <hip/hip_runtime.h>
#include <hip/hip_bf16.h>

typedef __bf16 bf16x8 __attribute__((ext_vector_type(8)));
typedef float f32x4 __attribute__((ext_vector_type(4)));
typedef float f32x16 __attribute__((ext_vector_type(16)));
typedef int i32x2 __attribute__((ext_vector_type(2)));
typedef int i32x4 __attribute__((ext_vector_type(4)));
typedef int i32x8 __attribute__((ext_vector_type(8)));
typedef unsigned int u32;

#define MFMA16 __builtin_amdgcn_mfma_f32_16x16x32_bf16
// MX-scaled fp8 MFMA, K=64, unity scales (E8M0 byte 0x7F = 2^0 in every lane-sel)
#define MFMASC(a, b, c) \
  __builtin_amdgcn_mfma_scale_f32_32x32x64_f8f6f4((a), (b), (c), 0, 0, 0, 0x7F7F7F7F, 0, 0x7F7F7F7F)

#define LOG2E 1.44269504f

__device__ __forceinline__ unsigned short f2b(float f) {
  return __builtin_bit_cast(unsigned short, (__bf16)f);
}

// pack 4 floats -> 4 fp8 e4m3 bytes (ascending)
__device__ __forceinline__ u32 pk4(float a, float b, float c, float d) {
  int v = __builtin_amdgcn_cvt_pk_fp8_f32(a, b, 0, false);
  v = __builtin_amdgcn_cvt_pk_fp8_f32(c, d, v, true);
  return (u32)v;
}

__device__ __forceinline__ void gload_lds16(const void* g, void* l) {
  __builtin_amdgcn_global_load_lds(
      (const __attribute__((address_space(1))) unsigned int*)g,
      (__attribute__((address_space(3))) unsigned int*)l, 16, 0, 0);
}

// ---------------------------------------------------------------------------
// Kernel 0: W (fp32) -> bf16
// ---------------------------------------------------------------------------
__global__ __launch_bounds__(256) void k_wconv(const float* __restrict__ Wa,
                                               const float* __restrict__ Wb,
                                               const float* __restrict__ Wm,
                                               unsigned short* __restrict__ W16) {
  const int m = blockIdx.y;
  const float* W = (m == 0) ? Wa : (m == 1) ? Wb : Wm;
  const int i = (blockIdx.x * 256 + threadIdx.x) * 8;
  float4 a = *reinterpret_cast<const float4*>(W + i);
  float4 b = *reinterpret_cast<const float4*>(W + i + 4);
  ushort4 lo, hi;
  lo.x = f2b(a.x); lo.y = f2b(a.y); lo.z = f2b(a.z); lo.w = f2b(a.w);
  hi.x = f2b(b.x); hi.y = f2b(b.y); hi.z = f2b(b.z); hi.w = f2b(b.w);
  unsigned short* dst = W16 + m * 65536 + i;
  *reinterpret_cast<ushort4*>(dst) = lo;
  *reinterpret_cast<ushort4*>(dst + 4) = hi;
}

// ---------------------------------------------------------------------------
// Kernel 1: fused transpose + 3 projections. 64 n-rows per block.
//   x -> LDS f32 tile -> XT_lds bf16 [64 n][256 c] (byte ^ (n&7)<<4 swizzle),
//   then Q8 (fp8, *log2e, swapped), K8 (fp8, swapped), V8 (fp8 blocked + BN).
// ---------------------------------------------------------------------------
__global__ __launch_bounds__(256) void k_proj(
    const float* __restrict__ x, const unsigned short* __restrict__ W16,
    const float* __restrict__ ba, const float* __restrict__ bb,
    const float* __restrict__ bm, const float* __restrict__ gamma,
    const float* __restrict__ beta, const float* __restrict__ rmean,
    const float* __restrict__ rvar,
    unsigned char* __restrict__ Q8, unsigned char* __restrict__ K8,
    unsigned char* __restrict__ V8) {
  __shared__ float tile[64][65];
  __shared__ __align__(16) unsigned short XT_lds[64 * 256];
  const int nt = blockIdx.x, b = blockIdx.y;
  const int n0 = nt * 64;
  const int tid = threadIdx.x, w = tid >> 6, l = tid & 63;
  const int li = l & 15, lk = l >> 4;
  const int j4 = (tid & 15) * 4, r0 = tid >> 4;
  // stage + transpose 4 c-tiles of 64
  for (int ct = 0; ct < 4; ++ct) {
    if (ct) __syncthreads();
#pragma unroll
    for (int p = 0; p < 4; ++p) {
      int r = r0 + p * 16;
      float4 v = *reinterpret_cast<const float4*>(
          x + ((size_t)(b * 256 + ct * 64 + r) * 4096) + n0 + j4);
      tile[r][j4] = v.x; tile[r][j4 + 1] = v.y; tile[r][j4 + 2] = v.z; tile[r][j4 + 3] = v.w;
    }
    __syncthreads();
#pragma unroll
    for (int p = 0; p < 4; ++p) {
      int r = r0 + p * 16;  // n-row within block
      ushort4 o;
      o.x = f2b(tile[j4][r]);
      o.y = f2b(tile[j4 + 1][r]);
      o.z = f2b(tile[j4 + 2][r]);
      o.w = f2b(tile[j4 + 3][r]);
      unsigned off = ((unsigned)(r * 512 + (ct * 64 + j4) * 2)) ^ (unsigned)((r & 7) << 4);
      *reinterpret_cast<ushort4*>((char*)XT_lds + off) = o;
    }
  }
  __syncthreads();
  // A-fragments: 16 rows per wave
  const int row = w * 16 + li;
  bf16x8 af[8];
#pragma unroll
  for (int kk = 0; kk < 8; ++kk) {
    unsigned off = ((unsigned)(row * 512 + kk * 64 + lk * 16)) ^ (unsigned)((row & 7) << 4);
    af[kk] = *reinterpret_cast<const bf16x8*>((const char*)XT_lds + off);
  }
  f32x4 zero = {0.f, 0.f, 0.f, 0.f};
  f32x4 acc[16];
  // ---- mode 0: Q (swapped MFMA -> lane holds 4 consecutive c) ----
  {
#pragma unroll
    for (int i = 0; i < 16; ++i) acc[i] = zero;
#pragma unroll
    for (int kk = 0; kk < 8; ++kk)
#pragma unroll
      for (int of = 0; of < 16; ++of) {
        bf16x8 bfv = *reinterpret_cast<const bf16x8*>(
            W16 + (size_t)(of * 16 + li) * 256 + kk * 32 + lk * 8);
        acc[of] = MFMA16(bfv, af[kk], acc[of], 0, 0, 0);
      }
    const int n = n0 + w * 16 + li;
    unsigned char* out = Q8 + ((size_t)b * 4096 + n) * 256;
#pragma unroll
    for (int of = 0; of < 16; ++of) {
      int c0 = of * 16 + lk * 4;
      float4 bs = *reinterpret_cast<const float4*>(ba + c0);
      u32 v = pk4((acc[of][0] + bs.x) * LOG2E, (acc[of][1] + bs.y) * LOG2E,
                  (acc[of][2] + bs.z) * LOG2E, (acc[of][3] + bs.w) * LOG2E);
      *reinterpret_cast<u32*>(out + c0) = v;
    }
  }
  // ---- mode 1: K (swapped) ----
  {
#pragma unroll
    for (int i = 0; i < 16; ++i) acc[i] = zero;
#pragma unroll
    for (int kk = 0; kk < 8; ++kk)
#pragma unroll
      for (int of = 0; of < 16; ++of) {
        bf16x8 bfv = *reinterpret_cast<const bf16x8*>(
            W16 + 65536 + (size_t)(of * 16 + li) * 256 + kk * 32 + lk * 8);
        acc[of] = MFMA16(bfv, af[kk], acc[of], 0, 0, 0);
      }
    const int n = n0 + w * 16 + li;
    unsigned char* out = K8 + ((size_t)b * 4096 + n) * 256;
#pragma unroll
    for (int of = 0; of < 16; ++of) {
      int c0 = of * 16 + lk * 4;
      float4 bs = *reinterpret_cast<const float4*>(bb + c0);
      u32 v = pk4(acc[of][0] + bs.x, acc[of][1] + bs.y,
                  acc[of][2] + bs.z, acc[of][3] + bs.w);
      *reinterpret_cast<u32*>(out + c0) = v;
    }
  }
  // ---- mode 2: V (normal orientation; lane holds 4 consecutive n) ----
  {
#pragma unroll
    for (int i = 0; i < 16; ++i) acc[i] = zero;
#pragma unroll
    for (int kk = 0; kk < 8; ++kk)
#pragma unroll
      for (int of = 0; of < 16; ++of) {
        bf16x8 bfv = *reinterpret_cast<const bf16x8*>(
            W16 + 131072 + (size_t)(of * 16 + li) * 256 + kk * 32 + lk * 8);
        acc[of] = MFMA16(af[kk], bfv, acc[of], 0, 0, 0);
      }
    const int nn0 = n0 + w * 16 + lk * 4;
#pragma unroll
    for (int of = 0; of < 16; ++of) {
      int c = of * 16 + li;
      float g = rsqrtf(rvar[c] + 1e-5f) * gamma[c];
      float sh = (bm[c] - rmean[c]) * g + beta[c];
      u32 v = pk4(acc[of][0] * g + sh, acc[of][1] * g + sh,
                  acc[of][2] * g + sh, acc[of][3] * g + sh);
      *reinterpret_cast<u32*>(V8 + (((size_t)b * 512 + (nn0 >> 3)) * 256 + c) * 8 + (nn0 & 7)) = v;
    }
  }
}

// ---------------------------------------------------------------------------
// Kernel 2: fp8 flash attention with MX-scaled K=64 MFMA (unity scales).
//   Grid 512 = 32 qt x 4 s x 4 b; 16 MFMAs per wave-tile (4x fewer than r5).
//   Softmax in exp2 domain (log2e pre-folded into Q8).
// ---------------------------------------------------------------------------
__global__ __launch_bounds__(256, 2) void k_attn(
    const unsigned char* __restrict__ Q8, const unsigned char* __restrict__ K8,
    const unsigned char* __restrict__ V8, unsigned short* __restrict__ part,
    float* __restrict__ mpart, float* __restrict__ lpart) {
  __shared__ __align__(16) unsigned char K_lds[2][64 * 256];  // [key][c], 32B-unit ^= key&7
  __shared__ __align__(16) unsigned char V_lds[2][8 * 2048];  // [slab][c][8], linear
  const int bid = blockIdx.x;
  const int swz = (bid & 7) * 64 + (bid >> 3);  // XCD-contiguous, bijective
  const int qt = swz & 31;
  const int bs = swz >> 5;
  const int b = bs >> 2, s = bs & 3;
  const int tid = threadIdx.x, w = tid >> 6, l = tid & 63;
  const int q = l & 31, hi = l >> 5;
  const int rowq = qt * 128 + w * 32 + q;
  // Q fp8 B-fragments: qf8[kk] = Q8[rowq][kk*64 + hi*32 .. +32]
  i32x8 qf8[4];
  const unsigned char* qp = Q8 + ((size_t)b * 4096 + rowq) * 256 + hi * 32;
#pragma unroll
  for (int kk = 0; kk < 4; ++kk) {
    i32x4 lo = *reinterpret_cast<const i32x4*>(qp + kk * 64);
    i32x4 hh = *reinterpret_cast<const i32x4*>(qp + kk * 64 + 16);
    qf8[kk] = (i32x8){lo[0], lo[1], lo[2], lo[3], hh[0], hh[1], hh[2], hh[3]};
  }
  f32x16 acc[8];
#pragma unroll
  for (int i = 0; i < 8; ++i)
#pragma unroll
    for (int r = 0; r < 16; ++r) acc[i][r] = 0.f;
  float mr = -3e38f, lr = 0.f;

  auto stageK = [&](int buf, int k0) {
#pragma unroll
    for (int g = 0; g < 4; ++g) {
      int row = w * 16 + g * 4 + (l >> 4);
      int c16 = (l & 15) ^ ((row & 7) << 1);  // inverse of 32B-unit XOR swizzle
      const unsigned char* src = K8 + ((size_t)b * 4096 + k0 + row) * 256 + c16 * 16;
      gload_lds16(src, &K_lds[buf][(w * 16 + g * 4) * 256]);
    }
  };
  auto stageV = [&](int buf, int k0) {
    const size_t k8b = (size_t)b * 512 + (k0 >> 3);
#pragma unroll
    for (int g = 0; g < 4; ++g) {
      int slab = w * 2 + (g >> 1);
      int pos = (g & 1) * 64 + l;
      const unsigned char* src = V8 + (k8b + slab) * 2048 + pos * 16;
      gload_lds16(src, &V_lds[buf][slab * 2048 + (g & 1) * 1024]);
    }
  };

  const int kbase = s * 1024;
  stageK(0, kbase);
  stageV(0, kbase);
  asm volatile("s_waitcnt vmcnt(0)" ::: "memory");
  __syncthreads();
  int cur = 0;
  for (int t = 0; t < 16; ++t) {
    if (t < 15) { stageK(cur ^ 1, kbase + (t + 1) * 64); stageV(cur ^ 1, kbase + (t + 1) * 64); }
    // ---- QK^T (swapped): S[key][q], keys 0-31 (S0) and 32-63 (S1) ----
    f32x16 S0, S1;
#pragma unroll
    for (int r = 0; r < 16; ++r) { S0[r] = 0.f; S1[r] = 0.f; }
    __builtin_amdgcn_s_setprio(1);
#pragma unroll
    for (int kk = 0; kk < 4; ++kk) {
      int off = ((kk * 2 + hi) ^ (q & 7)) << 5;
      const unsigned char* kr0 = &K_lds[cur][q * 256 + off];
      const unsigned char* kr1 = &K_lds[cur][(32 + q) * 256 + off];
      i32x4 a0 = *reinterpret_cast<const i32x4*>(kr0);
      i32x4 a1 = *reinterpret_cast<const i32x4*>(kr0 + 16);
      i32x4 b0 = *reinterpret_cast<const i32x4*>(kr1);
      i32x4 b1 = *reinterpret_cast<const i32x4*>(kr1 + 16);
      i32x8 kf0 = (i32x8){a0[0], a0[1], a0[2], a0[3], a1[0], a1[1], a1[2], a1[3]};
      i32x8 kf1 = (i32x8){b0[0], b0[1], b0[2], b0[3], b1[0], b1[1], b1[2], b1[3]};
      S0 = MFMASC(kf0, qf8[kk], S0);
      S1 = MFMASC(kf1, qf8[kk], S1);
    }
    __builtin_amdgcn_s_setprio(0);
    // ---- online softmax, exp2 domain ----
    float pmax = fmaxf(S0[0], S1[0]);
#pragma unroll
    for (int r = 1; r < 16; ++r) pmax = fmaxf(pmax, fmaxf(S0[r], S1[r]));
    pmax = fmaxf(pmax, __shfl_xor(pmax, 32));
    if (!__all(pmax - mr <= 7.0f)) {  // defer-max: p <= 2^7 = 128 < 448 fp8 max
      float nm = fmaxf(mr, pmax);
      float sc = exp2f(mr - nm);
      mr = nm;
      lr *= sc;
#pragma unroll
      for (int cb = 0; cb < 8; ++cb)
#pragma unroll
        for (int r = 0; r < 16; ++r) acc[cb][r] *= sc;
    }
    float p0[16], p1[16];
    float sum = 0.f;
#pragma unroll
    for (int r = 0; r < 16; ++r) { p0[r] = exp2f(S0[r] - mr); sum += p0[r]; }
#pragma unroll
    for (int r = 0; r < 16; ++r) { p1[r] = exp2f(S1[r] - mr); sum += p1[r]; }
    sum += __shfl_xor(sum, 32);
    lr += sum;
    // ---- P -> fp8 B-frag in registers ----
    // lane(q,hi) reg r of S0 holds key (r&3)+4*hi+8*(r>>2); S1 same +32.
    // swap(Ai,Bi): hi=0 lane gets [own Ai | partner Ai] = keys 8i..8i+7;
    //              hi=1 lane gets [partner Bi | own Bi] = keys 32+8i..+7.
    // B-frag (K=64): lane half hi supplies keys hi*32..+31 ascending ✓
    u32 A0 = pk4(p0[0], p0[1], p0[2], p0[3]);
    u32 A1 = pk4(p0[4], p0[5], p0[6], p0[7]);
    u32 A2 = pk4(p0[8], p0[9], p0[10], p0[11]);
    u32 A3 = pk4(p0[12], p0[13], p0[14], p0[15]);
    u32 B0 = pk4(p1[0], p1[1], p1[2], p1[3]);
    u32 B1 = pk4(p1[4], p1[5], p1[6], p1[7]);
    u32 B2 = pk4(p1[8], p1[9], p1[10], p1[11]);
    u32 B3 = pk4(p1[12], p1[13], p1[14], p1[15]);
    asm volatile("v_permlane32_swap_b32 %0, %1" : "+v"(A0), "+v"(B0));
    asm volatile("v_permlane32_swap_b32 %0, %1" : "+v"(A1), "+v"(B1));
    asm volatile("v_permlane32_swap_b32 %0, %1" : "+v"(A2), "+v"(B2));
    asm volatile("v_permlane32_swap_b32 %0, %1" : "+v"(A3), "+v"(B3));
    i32x8 pb = (i32x8){(int)A0, (int)B0, (int)A1, (int)B1,
                       (int)A2, (int)B2, (int)A3, (int)B3};
    // ---- PV as O^T: one K=64 MFMA per 32-channel block ----
    __builtin_amdgcn_s_setprio(1);
#pragma unroll
    for (int cb = 0; cb < 8; ++cb) {
      const unsigned char* vb = &V_lds[cur][(hi * 4) * 2048 + (cb * 32 + q) * 8];
      i32x2 v0 = *reinterpret_cast<const i32x2*>(vb);
      i32x2 v1 = *reinterpret_cast<const i32x2*>(vb + 2048);
      i32x2 v2 = *reinterpret_cast<const i32x2*>(vb + 4096);
      i32x2 v3 = *reinterpret_cast<const i32x2*>(vb + 6144);
      i32x8 vf = (i32x8){v0[0], v0[1], v1[0], v1[1], v2[0], v2[1], v3[0], v3[1]};
      acc[cb] = MFMASC(vf, pb, acc[cb]);
    }
    __builtin_amdgcn_s_setprio(0);
    asm volatile("s_waitcnt vmcnt(0)" ::: "memory");
    __syncthreads();
    cur ^= 1;
  }
  // ---- store partial: c = cb*32 + (r&3) + 8*(r>>2) + 4*hi ----
  const int sb = s * 4 + b;
  size_t pbase = ((size_t)sb * 4096 + rowq) * 256;
#pragma unroll
  for (int cb = 0; cb < 8; ++cb)
#pragma unroll
    for (int g = 0; g < 4; ++g) {
      ushort4 o;
      o.x = f2b(acc[cb][g * 4 + 0]); o.y = f2b(acc[cb][g * 4 + 1]);
      o.z = f2b(acc[cb][g * 4 + 2]); o.w = f2b(acc[cb][g * 4 + 3]);
      *reinterpret_cast<ushort4*>(&part[pbase + cb * 32 + g * 8 + hi * 4]) = o;
    }
  if (hi == 0) {
    mpart[sb * 4096 + rowq] = mr;
    lpart[sb * 4096 + rowq] = lr;
  }
}

// ---------------------------------------------------------------------------
// Kernel 3: combine splits (exp2 domain) + residual epilogue
// ---------------------------------------------------------------------------
__global__ __launch_bounds__(256) void k_comb(
    const unsigned short* __restrict__ part, const float* __restrict__ mpart,
    const float* __restrict__ lpart, const float* __restrict__ feat,
    const float* __restrict__ alpha, float* __restrict__ out) {
  __shared__ float wgt[4][64];
  __shared__ float tile[64][261];
  const int nt = blockIdx.x, b = blockIdx.y;
  const int n0 = nt * 64;
  const int tid = threadIdx.x;
  if (tid < 64) {
    int qn = n0 + tid;
    float m[4], lv[4];
#pragma unroll
    for (int s = 0; s < 4; ++s) {
      m[s] = mpart[(s * 4 + b) * 4096 + qn];
      lv[s] = lpart[(s * 4 + b) * 4096 + qn];
    }
    float M = fmaxf(fmaxf(m[0], m[1]), fmaxf(m[2], m[3]));
    float e[4], L = 0.f;
#pragma unroll
    for (int s = 0; s < 4; ++s) { e[s] = exp2f(m[s] - M); L += e[s] * lv[s]; }
    float inv = 1.0f / L;
#pragma unroll
    for (int s = 0; s < 4; ++s) wgt[s][tid] = e[s] * inv;
  }
  __syncthreads();
  const int row = tid >> 2;
  const int c0 = (tid & 3) * 64;
  float acc[64];
#pragma unroll
  for (int k = 0; k < 64; ++k) acc[k] = 0.f;
  for (int s = 0; s < 4; ++s) {
    float ww = wgt[s][row];
    const unsigned short* p = part + (((size_t)(s * 4 + b)) * 4096 + n0 + row) * 256 + c0;
#pragma unroll
    for (int ch = 0; ch < 8; ++ch) {
      bf16x8 v = *reinterpret_cast<const bf16x8*>(p + ch * 8);
#pragma unroll
      for (int j = 0; j < 8; ++j) acc[ch * 8 + j] += ww * (float)v[j];
    }
  }
#pragma unroll
  for (int k = 0; k < 64; ++k) tile[row][c0 + k] = acc[k];
  __syncthreads();
  const float av = alpha[0];
  const int j = tid & 15, cb = tid >> 4;
#pragma unroll
  for (int p = 0; p < 16; ++p) {
    int c = cb * 16 + p;
    size_t gbase = ((size_t)(b * 256 + c)) * 4096 + n0 + j * 4;
    float4 f4 = *reinterpret_cast<const float4*>(feat + gbase);
    float4 o;
    o.x = f4.x + av * tile[j * 4 + 0][c];
    o.y = f4.y + av * tile[j * 4 + 1][c];
    o.z = f4.z + av * tile[j * 4 + 2][c];
    o.w = f4.w + av * tile[j * 4 + 3][c];
    *reinterpret_cast<float4*>(out + gbase) = o;
  }
}

extern "C" void kernel_launch(void* const* d_in, const int* in_sizes, int n_in,
                              void* d_out, int out_size, void* d_ws, size_t ws_size,
                              hipStream_t stream) {
  const float* feat  = (const float*)d_in[0];
  const float* Wa    = (const float*)d_in[1];
  const float* ba    = (const float*)d_in[2];
  const float* Wb    = (const float*)d_in[3];
  const float* bb    = (const float*)d_in[4];
  const float* Wm    = (const float*)d_in[5];
  const float* bm    = (const float*)d_in[6];
  const float* gamma = (const float*)d_in[7];
  const float* beta  = (const float*)d_in[8];
  const float* rmean = (const float*)d_in[9];
  const float* rvar  = (const float*)d_in[10];
  const float* alpha = (const float*)d_in[11];
  float* out = (float*)d_out;
  char* ws = (char*)d_ws;
  unsigned char*  Q8   = (unsigned char*)(ws);                        // [0,4M) fp8 [b][n][c] (*log2e)
  unsigned char*  K8   = (unsigned char*)(ws + ((size_t)4 << 20));    // [4M,8M) fp8 [b][n][c]
  unsigned char*  V8   = (unsigned char*)(ws + ((size_t)8 << 20));    // [8M,12M) fp8 [b][k8][c][8]
  unsigned short* part = (unsigned short*)(ws + ((size_t)16 << 20));  // [16M,48M) bf16
  unsigned short* W16  = (unsigned short*)(ws + ((size_t)48 << 20));  // 384K bf16
  float* mpart = (float*)(ws + ((size_t)48 << 20) + 393216);
  float* lpart = (float*)(ws + ((size_t)48 << 20) + 393216 + 262144);

  k_wconv<<<dim3(32, 3), 256, 0, stream>>>(Wa, Wb, Wm, W16);
  k_proj<<<dim3(64, 4), 256, 0, stream>>>(feat, W16, ba, bb, bm, gamma, beta,
                                          rmean, rvar, Q8, K8, V8);
  k_attn<<<dim3(512), 256, 0, stream>>>(Q8, K8, V8, part, mpart, lpart);
  k_comb<<<dim3(64, 4), 256, 0, stream>>>(part, mpart, lpart, feat, alpha, out);
}

// Round 7
// 121.231 us; speedup vs baseline: 1.4726x; 1.4726x over previous
//
#include <hip/hip_runtime.h>
#include <hip/hip_bf16.h>

typedef __bf16 bf16x8 __attribute__((ext_vector_type(8)));
typedef float f32x4 __attribute__((ext_vector_type(4)));
typedef float f32x16 __attribute__((ext_vector_type(16)));
typedef int i32x2 __attribute__((ext_vector_type(2)));
typedef int i32x4 __attribute__((ext_vector_type(4)));
typedef int i32x8 __attribute__((ext_vector_type(8)));
typedef unsigned int u32;

#define MFMA16 __builtin_amdgcn_mfma_f32_16x16x32_bf16
// MX-scaled fp8 MFMA, K=64, unity scales (E8M0 byte 0x7F = 2^0 in every lane-sel)
#define MFMASC(a, b, c) \
  __builtin_amdgcn_mfma_scale_f32_32x32x64_f8f6f4((a), (b), (c), 0, 0, 0, 0x7F7F7F7F, 0, 0x7F7F7F7F)

#define LOG2E 1.44269504f

__device__ __forceinline__ unsigned short f2b(float f) {
  return __builtin_bit_cast(unsigned short, (__bf16)f);
}

// pack 4 floats -> 4 fp8 e4m3 bytes (ascending)
__device__ __forceinline__ u32 pk4(float a, float b, float c, float d) {
  int v = __builtin_amdgcn_cvt_pk_fp8_f32(a, b, 0, false);
  v = __builtin_amdgcn_cvt_pk_fp8_f32(c, d, v, true);
  return (u32)v;
}

__device__ __forceinline__ void gload_lds16(const void* g, void* l) {
  __builtin_amdgcn_global_load_lds(
      (const __attribute__((address_space(1))) unsigned int*)g,
      (__attribute__((address_space(3))) unsigned int*)l, 16, 0, 0);
}

// ---------------------------------------------------------------------------
// Kernel 0: W (fp32) -> bf16
// ---------------------------------------------------------------------------
__global__ __launch_bounds__(256) void k_wconv(const float* __restrict__ Wa,
                                               const float* __restrict__ Wb,
                                               const float* __restrict__ Wm,
                                               unsigned short* __restrict__ W16) {
  const int m = blockIdx.y;
  const float* W = (m == 0) ? Wa : (m == 1) ? Wb : Wm;
  const int i = (blockIdx.x * 256 + threadIdx.x) * 8;
  float4 a = *reinterpret_cast<const float4*>(W + i);
  float4 b = *reinterpret_cast<const float4*>(W + i + 4);
  ushort4 lo, hi;
  lo.x = f2b(a.x); lo.y = f2b(a.y); lo.z = f2b(a.z); lo.w = f2b(a.w);
  hi.x = f2b(b.x); hi.y = f2b(b.y); hi.z = f2b(b.z); hi.w = f2b(b.w);
  unsigned short* dst = W16 + m * 65536 + i;
  *reinterpret_cast<ushort4*>(dst) = lo;
  *reinterpret_cast<ushort4*>(dst + 4) = hi;
}

// ---------------------------------------------------------------------------
// Kernel 1: fused transpose + 3 projections. 32 n-rows/block, grid (128,4)
//   = 512 blocks (2/CU). Waves split the `of` (output-channel) dimension:
//   each wave = 4 of-slices x 32 rows x 3 modes -> 2 MFMAs per W-load and
//   a 4x shorter per-wave dependency chain than r6 (which was 1 blk/CU,
//   MfmaUtil 2.4%, latency-bound).
// ---------------------------------------------------------------------------
__global__ __launch_bounds__(256) void k_proj(
    const float* __restrict__ x, const unsigned short* __restrict__ W16,
    const float* __restrict__ ba, const float* __restrict__ bb,
    const float* __restrict__ bm, const float* __restrict__ gamma,
    const float* __restrict__ beta, const float* __restrict__ rmean,
    const float* __restrict__ rvar,
    unsigned char* __restrict__ Q8, unsigned char* __restrict__ K8,
    unsigned char* __restrict__ V8) {
  __shared__ float tile[256][33];  // [c][n], +1 pad
  __shared__ __align__(16) unsigned short XT_lds[32 * 256];  // [n][c] bf16, swizzled
  const int nt = blockIdx.x, b = blockIdx.y;
  const int n0 = nt * 32;
  const int tid = threadIdx.x, w = tid >> 6, l = tid & 63;
  const int li = l & 15, lk = l >> 4;
  // ---- load x[b][c][n0..n0+32): 8 passes, thread -> (c, 4 n's) ----
  {
    const int cr = tid >> 3, j4 = (tid & 7) * 4;
#pragma unroll
    for (int p = 0; p < 8; ++p) {
      int c = p * 32 + cr;
      float4 v = *reinterpret_cast<const float4*>(
          x + ((size_t)(b * 256 + c)) * 4096 + n0 + j4);
      tile[c][j4] = v.x; tile[c][j4 + 1] = v.y;
      tile[c][j4 + 2] = v.z; tile[c][j4 + 3] = v.w;
    }
  }
  __syncthreads();
  // ---- transpose + cvt -> XT_lds[n][c], byte ^ (n&7)<<4 swizzle ----
  {
    const int n = tid & 31, cb8 = (tid >> 5) * 32;
#pragma unroll
    for (int p = 0; p < 8; ++p) {
      int c0 = cb8 + p * 4;
      ushort4 o;
      o.x = f2b(tile[c0][n]); o.y = f2b(tile[c0 + 1][n]);
      o.z = f2b(tile[c0 + 2][n]); o.w = f2b(tile[c0 + 3][n]);
      unsigned off = ((unsigned)(n * 512 + c0 * 2)) ^ (unsigned)((n & 7) << 4);
      *reinterpret_cast<ushort4*>((char*)XT_lds + off) = o;
    }
  }
  __syncthreads();
  // ---- A-fragments: both 16-row sets (each wave needs all 32 rows) ----
  bf16x8 af[2][8];
#pragma unroll
  for (int rs = 0; rs < 2; ++rs) {
    const int row = rs * 16 + li;
#pragma unroll
    for (int kk = 0; kk < 8; ++kk) {
      unsigned off = ((unsigned)(row * 512 + kk * 64 + lk * 16)) ^ (unsigned)((row & 7) << 4);
      af[rs][kk] = *reinterpret_cast<const bf16x8*>((const char*)XT_lds + off);
    }
  }
  const int ofb = w * 4;  // this wave's 4 of-slices
  f32x4 zero = {0.f, 0.f, 0.f, 0.f};
  f32x4 acc[2][4];
  // ---- mode 0: Q (swapped MFMA -> lane holds 4 consecutive c), *log2e ----
  {
#pragma unroll
    for (int rs = 0; rs < 2; ++rs)
#pragma unroll
      for (int i = 0; i < 4; ++i) acc[rs][i] = zero;
#pragma unroll
    for (int kk = 0; kk < 8; ++kk)
#pragma unroll
      for (int of = 0; of < 4; ++of) {
        bf16x8 bfv = *reinterpret_cast<const bf16x8*>(
            W16 + (size_t)((ofb + of) * 16 + li) * 256 + kk * 32 + lk * 8);
        acc[0][of] = MFMA16(bfv, af[0][kk], acc[0][of], 0, 0, 0);
        acc[1][of] = MFMA16(bfv, af[1][kk], acc[1][of], 0, 0, 0);
      }
#pragma unroll
    for (int rs = 0; rs < 2; ++rs) {
      const int n = n0 + rs * 16 + li;
      unsigned char* out = Q8 + ((size_t)b * 4096 + n) * 256;
#pragma unroll
      for (int of = 0; of < 4; ++of) {
        int c0 = (ofb + of) * 16 + lk * 4;
        float4 bs = *reinterpret_cast<const float4*>(ba + c0);
        u32 v = pk4((acc[rs][of][0] + bs.x) * LOG2E, (acc[rs][of][1] + bs.y) * LOG2E,
                    (acc[rs][of][2] + bs.z) * LOG2E, (acc[rs][of][3] + bs.w) * LOG2E);
        *reinterpret_cast<u32*>(out + c0) = v;
      }
    }
  }
  // ---- mode 1: K (swapped) ----
  {
#pragma unroll
    for (int rs = 0; rs < 2; ++rs)
#pragma unroll
      for (int i = 0; i < 4; ++i) acc[rs][i] = zero;
#pragma unroll
    for (int kk = 0; kk < 8; ++kk)
#pragma unroll
      for (int of = 0; of < 4; ++of) {
        bf16x8 bfv = *reinterpret_cast<const bf16x8*>(
            W16 + 65536 + (size_t)((ofb + of) * 16 + li) * 256 + kk * 32 + lk * 8);
        acc[0][of] = MFMA16(bfv, af[0][kk], acc[0][of], 0, 0, 0);
        acc[1][of] = MFMA16(bfv, af[1][kk], acc[1][of], 0, 0, 0);
      }
#pragma unroll
    for (int rs = 0; rs < 2; ++rs) {
      const int n = n0 + rs * 16 + li;
      unsigned char* out = K8 + ((size_t)b * 4096 + n) * 256;
#pragma unroll
      for (int of = 0; of < 4; ++of) {
        int c0 = (ofb + of) * 16 + lk * 4;
        float4 bs = *reinterpret_cast<const float4*>(bb + c0);
        u32 v = pk4(acc[rs][of][0] + bs.x, acc[rs][of][1] + bs.y,
                    acc[rs][of][2] + bs.z, acc[rs][of][3] + bs.w);
        *reinterpret_cast<u32*>(out + c0) = v;
      }
    }
  }
  // ---- mode 2: V (normal orientation; lane holds 4 consecutive n) + BN ----
  {
#pragma unroll
    for (int rs = 0; rs < 2; ++rs)
#pragma unroll
      for (int i = 0; i < 4; ++i) acc[rs][i] = zero;
#pragma unroll
    for (int kk = 0; kk < 8; ++kk)
#pragma unroll
      for (int of = 0; of < 4; ++of) {
        bf16x8 bfv = *reinterpret_cast<const bf16x8*>(
            W16 + 131072 + (size_t)((ofb + of) * 16 + li) * 256 + kk * 32 + lk * 8);
        acc[0][of] = MFMA16(af[0][kk], bfv, acc[0][of], 0, 0, 0);
        acc[1][of] = MFMA16(af[1][kk], bfv, acc[1][of], 0, 0, 0);
      }
#pragma unroll
    for (int of = 0; of < 4; ++of) {
      int c = (ofb + of) * 16 + li;
      float g = rsqrtf(rvar[c] + 1e-5f) * gamma[c];
      float sh = (bm[c] - rmean[c]) * g + beta[c];
#pragma unroll
      for (int rs = 0; rs < 2; ++rs) {
        const int nn0 = n0 + rs * 16 + lk * 4;
        u32 v = pk4(acc[rs][of][0] * g + sh, acc[rs][of][1] * g + sh,
                    acc[rs][of][2] * g + sh, acc[rs][of][3] * g + sh);
        *reinterpret_cast<u32*>(V8 + (((size_t)b * 512 + (nn0 >> 3)) * 256 + c) * 8 + (nn0 & 7)) = v;
      }
    }
  }
}

// ---------------------------------------------------------------------------
// Kernel 2: fp8 flash attention with MX-scaled K=64 MFMA (unity scales).
//   Grid 512 = 32 qt x 4 s x 4 b; softmax in exp2 domain.
// ---------------------------------------------------------------------------
__global__ __launch_bounds__(256, 2) void k_attn(
    const unsigned char* __restrict__ Q8, const unsigned char* __restrict__ K8,
    const unsigned char* __restrict__ V8, unsigned short* __restrict__ part,
    float* __restrict__ mpart, float* __restrict__ lpart) {
  __shared__ __align__(16) unsigned char K_lds[2][64 * 256];  // [key][c], 32B-unit ^= key&7
  __shared__ __align__(16) unsigned char V_lds[2][8 * 2048];  // [slab][c][8], linear
  const int bid = blockIdx.x;
  const int swz = (bid & 7) * 64 + (bid >> 3);  // XCD-contiguous, bijective
  const int qt = swz & 31;
  const int bs = swz >> 5;
  const int b = bs >> 2, s = bs & 3;
  const int tid = threadIdx.x, w = tid >> 6, l = tid & 63;
  const int q = l & 31, hi = l >> 5;
  const int rowq = qt * 128 + w * 32 + q;
  // Q fp8 B-fragments: qf8[kk] = Q8[rowq][kk*64 + hi*32 .. +32]
  i32x8 qf8[4];
  const unsigned char* qp = Q8 + ((size_t)b * 4096 + rowq) * 256 + hi * 32;
#pragma unroll
  for (int kk = 0; kk < 4; ++kk) {
    i32x4 lo = *reinterpret_cast<const i32x4*>(qp + kk * 64);
    i32x4 hh = *reinterpret_cast<const i32x4*>(qp + kk * 64 + 16);
    qf8[kk] = (i32x8){lo[0], lo[1], lo[2], lo[3], hh[0], hh[1], hh[2], hh[3]};
  }
  f32x16 acc[8];
#pragma unroll
  for (int i = 0; i < 8; ++i)
#pragma unroll
    for (int r = 0; r < 16; ++r) acc[i][r] = 0.f;
  float mr = -3e38f, lr = 0.f;

  auto stageK = [&](int buf, int k0) {
#pragma unroll
    for (int g = 0; g < 4; ++g) {
      int row = w * 16 + g * 4 + (l >> 4);
      int c16 = (l & 15) ^ ((row & 7) << 1);  // inverse of 32B-unit XOR swizzle
      const unsigned char* src = K8 + ((size_t)b * 4096 + k0 + row) * 256 + c16 * 16;
      gload_lds16(src, &K_lds[buf][(w * 16 + g * 4) * 256]);
    }
  };
  auto stageV = [&](int buf, int k0) {
    const size_t k8b = (size_t)b * 512 + (k0 >> 3);
#pragma unroll
    for (int g = 0; g < 4; ++g) {
      int slab = w * 2 + (g >> 1);
      int pos = (g & 1) * 64 + l;
      const unsigned char* src = V8 + (k8b + slab) * 2048 + pos * 16;
      gload_lds16(src, &V_lds[buf][slab * 2048 + (g & 1) * 1024]);
    }
  };

  const int kbase = s * 1024;
  stageK(0, kbase);
  stageV(0, kbase);
  asm volatile("s_waitcnt vmcnt(0)" ::: "memory");
  __syncthreads();
  int cur = 0;
  for (int t = 0; t < 16; ++t) {
    if (t < 15) { stageK(cur ^ 1, kbase + (t + 1) * 64); stageV(cur ^ 1, kbase + (t + 1) * 64); }
    // ---- QK^T (swapped): S[key][q], keys 0-31 (S0) and 32-63 (S1) ----
    f32x16 S0, S1;
#pragma unroll
    for (int r = 0; r < 16; ++r) { S0[r] = 0.f; S1[r] = 0.f; }
    __builtin_amdgcn_s_setprio(1);
#pragma unroll
    for (int kk = 0; kk < 4; ++kk) {
      int off = ((kk * 2 + hi) ^ (q & 7)) << 5;
      const unsigned char* kr0 = &K_lds[cur][q * 256 + off];
      const unsigned char* kr1 = &K_lds[cur][(32 + q) * 256 + off];
      i32x4 a0 = *reinterpret_cast<const i32x4*>(kr0);
      i32x4 a1 = *reinterpret_cast<const i32x4*>(kr0 + 16);
      i32x4 b0 = *reinterpret_cast<const i32x4*>(kr1);
      i32x4 b1 = *reinterpret_cast<const i32x4*>(kr1 + 16);
      i32x8 kf0 = (i32x8){a0[0], a0[1], a0[2], a0[3], a1[0], a1[1], a1[2], a1[3]};
      i32x8 kf1 = (i32x8){b0[0], b0[1], b0[2], b0[3], b1[0], b1[1], b1[2], b1[3]};
      S0 = MFMASC(kf0, qf8[kk], S0);
      S1 = MFMASC(kf1, qf8[kk], S1);
    }
    __builtin_amdgcn_s_setprio(0);
    // ---- online softmax, exp2 domain ----
    float pmax = fmaxf(S0[0], S1[0]);
#pragma unroll
    for (int r = 1; r < 16; ++r) pmax = fmaxf(pmax, fmaxf(S0[r], S1[r]));
    pmax = fmaxf(pmax, __shfl_xor(pmax, 32));
    if (!__all(pmax - mr <= 7.0f)) {  // defer-max: p <= 2^7 = 128 < 448 fp8 max
      float nm = fmaxf(mr, pmax);
      float sc = exp2f(mr - nm);
      mr = nm;
      lr *= sc;
#pragma unroll
      for (int cb = 0; cb < 8; ++cb)
#pragma unroll
        for (int r = 0; r < 16; ++r) acc[cb][r] *= sc;
    }
    float p0[16], p1[16];
    float sum = 0.f;
#pragma unroll
    for (int r = 0; r < 16; ++r) { p0[r] = exp2f(S0[r] - mr); sum += p0[r]; }
#pragma unroll
    for (int r = 0; r < 16; ++r) { p1[r] = exp2f(S1[r] - mr); sum += p1[r]; }
    sum += __shfl_xor(sum, 32);
    lr += sum;
    // ---- P -> fp8 B-frag in registers (cvt_pk + permlane32_swap) ----
    u32 A0 = pk4(p0[0], p0[1], p0[2], p0[3]);
    u32 A1 = pk4(p0[4], p0[5], p0[6], p0[7]);
    u32 A2 = pk4(p0[8], p0[9], p0[10], p0[11]);
    u32 A3 = pk4(p0[12], p0[13], p0[14], p0[15]);
    u32 B0 = pk4(p1[0], p1[1], p1[2], p1[3]);
    u32 B1 = pk4(p1[4], p1[5], p1[6], p1[7]);
    u32 B2 = pk4(p1[8], p1[9], p1[10], p1[11]);
    u32 B3 = pk4(p1[12], p1[13], p1[14], p1[15]);
    asm volatile("v_permlane32_swap_b32 %0, %1" : "+v"(A0), "+v"(B0));
    asm volatile("v_permlane32_swap_b32 %0, %1" : "+v"(A1), "+v"(B1));
    asm volatile("v_permlane32_swap_b32 %0, %1" : "+v"(A2), "+v"(B2));
    asm volatile("v_permlane32_swap_b32 %0, %1" : "+v"(A3), "+v"(B3));
    i32x8 pb = (i32x8){(int)A0, (int)B0, (int)A1, (int)B1,
                       (int)A2, (int)B2, (int)A3, (int)B3};
    // ---- PV as O^T: one K=64 MFMA per 32-channel block ----
    __builtin_amdgcn_s_setprio(1);
#pragma unroll
    for (int cb = 0; cb < 8; ++cb) {
      const unsigned char* vb = &V_lds[cur][(hi * 4) * 2048 + (cb * 32 + q) * 8];
      i32x2 v0 = *reinterpret_cast<const i32x2*>(vb);
      i32x2 v1 = *reinterpret_cast<const i32x2*>(vb + 2048);
      i32x2 v2 = *reinterpret_cast<const i32x2*>(vb + 4096);
      i32x2 v3 = *reinterpret_cast<const i32x2*>(vb + 6144);
      i32x8 vf = (i32x8){v0[0], v0[1], v1[0], v1[1], v2[0], v2[1], v3[0], v3[1]};
      acc[cb] = MFMASC(vf, pb, acc[cb]);
    }
    __builtin_amdgcn_s_setprio(0);
    asm volatile("s_waitcnt vmcnt(0)" ::: "memory");
    __syncthreads();
    cur ^= 1;
  }
  // ---- store partial: c = cb*32 + (r&3) + 8*(r>>2) + 4*hi ----
  const int sb = s * 4 + b;
  size_t pbase = ((size_t)sb * 4096 + rowq) * 256;
#pragma unroll
  for (int cb = 0; cb < 8; ++cb)
#pragma unroll
    for (int g = 0; g < 4; ++g) {
      ushort4 o;
      o.x = f2b(acc[cb][g * 4 + 0]); o.y = f2b(acc[cb][g * 4 + 1]);
      o.z = f2b(acc[cb][g * 4 + 2]); o.w = f2b(acc[cb][g * 4 + 3]);
      *reinterpret_cast<ushort4*>(&part[pbase + cb * 32 + g * 8 + hi * 4]) = o;
    }
  if (hi == 0) {
    mpart[sb * 4096 + rowq] = mr;
    lpart[sb * 4096 + rowq] = lr;
  }
}

// ---------------------------------------------------------------------------
// Kernel 3: combine splits (exp2 domain) + residual epilogue
// ---------------------------------------------------------------------------
__global__ __launch_bounds__(256) void k_comb(
    const unsigned short* __restrict__ part, const float* __restrict__ mpart,
    const float* __restrict__ lpart, const float* __restrict__ feat,
    const float* __restrict__ alpha, float* __restrict__ out) {
  __shared__ float wgt[4][64];
  __shared__ float tile[64][261];
  const int nt = blockIdx.x, b = blockIdx.y;
  const int n0 = nt * 64;
  const int tid = threadIdx.x;
  if (tid < 64) {
    int qn = n0 + tid;
    float m[4], lv[4];
#pragma unroll
    for (int s = 0; s < 4; ++s) {
      m[s] = mpart[(s * 4 + b) * 4096 + qn];
      lv[s] = lpart[(s * 4 + b) * 4096 + qn];
    }
    float M = fmaxf(fmaxf(m[0], m[1]), fmaxf(m[2], m[3]));
    float e[4], L = 0.f;
#pragma unroll
    for (int s = 0; s < 4; ++s) { e[s] = exp2f(m[s] - M); L += e[s] * lv[s]; }
    float inv = 1.0f / L;
#pragma unroll
    for (int s = 0; s < 4; ++s) wgt[s][tid] = e[s] * inv;
  }
  __syncthreads();
  const int row = tid >> 2;
  const int c0 = (tid & 3) * 64;
  float acc[64];
#pragma unroll
  for (int k = 0; k < 64; ++k) acc[k] = 0.f;
  for (int s = 0; s < 4; ++s) {
    float ww = wgt[s][row];
    const unsigned short* p = part + (((size_t)(s * 4 + b)) * 4096 + n0 + row) * 256 + c0;
#pragma unroll
    for (int ch = 0; ch < 8; ++ch) {
      bf16x8 v = *reinterpret_cast<const bf16x8*>(p + ch * 8);
#pragma unroll
      for (int j = 0; j < 8; ++j) acc[ch * 8 + j] += ww * (float)v[j];
    }
  }
#pragma unroll
  for (int k = 0; k < 64; ++k) tile[row][c0 + k] = acc[k];
  __syncthreads();
  const float av = alpha[0];
  const int j = tid & 15, cb = tid >> 4;
#pragma unroll
  for (int p = 0; p < 16; ++p) {
    int c = cb * 16 + p;
    size_t gbase = ((size_t)(b * 256 + c)) * 4096 + n0 + j * 4;
    float4 f4 = *reinterpret_cast<const float4*>(feat + gbase);
    float4 o;
    o.x = f4.x + av * tile[j * 4 + 0][c];
    o.y = f4.y + av * tile[j * 4 + 1][c];
    o.z = f4.z + av * tile[j * 4 + 2][c];
    o.w = f4.w + av * tile[j * 4 + 3][c];
    *reinterpret_cast<float4*>(out + gbase) = o;
  }
}

extern "C" void kernel_launch(void* const* d_in, const int* in_sizes, int n_in,
                              void* d_out, int out_size, void* d_ws, size_t ws_size,
                              hipStream_t stream) {
  const float* feat  = (const float*)d_in[0];
  const float* Wa    = (const float*)d_in[1];
  const float* ba    = (const float*)d_in[2];
  const float* Wb    = (const float*)d_in[3];
  const float* bb    = (const float*)d_in[4];
  const float* Wm    = (const float*)d_in[5];
  const float* bm    = (const float*)d_in[6];
  const float* gamma = (const float*)d_in[7];
  const float* beta  = (const float*)d_in[8];
  const float* rmean = (const float*)d_in[9];
  const float* rvar  = (const float*)d_in[10];
  const float* alpha = (const float*)d_in[11];
  float* out = (float*)d_out;
  char* ws = (char*)d_ws;
  unsigned char*  Q8   = (unsigned char*)(ws);                        // [0,4M) fp8 [b][n][c] (*log2e)
  unsigned char*  K8   = (unsigned char*)(ws + ((size_t)4 << 20));    // [4M,8M) fp8 [b][n][c]
  unsigned char*  V8   = (unsigned char*)(ws + ((size_t)8 << 20));    // [8M,12M) fp8 [b][k8][c][8]
  unsigned short* part = (unsigned short*)(ws + ((size_t)16 << 20));  // [16M,48M) bf16
  unsigned short* W16  = (unsigned short*)(ws + ((size_t)48 << 20));  // 384K bf16
  float* mpart = (float*)(ws + ((size_t)48 << 20) + 393216);
  float* lpart = (float*)(ws + ((size_t)48 << 20) + 393216 + 262144);

  k_wconv<<<dim3(32, 3), 256, 0, stream>>>(Wa, Wb, Wm, W16);
  k_proj<<<dim3(128, 4), 256, 0, stream>>>(feat, W16, ba, bb, bm, gamma, beta,
                                           rmean, rvar, Q8, K8, V8);
  k_attn<<<dim3(512), 256, 0, stream>>>(Q8, K8, V8, part, mpart, lpart);
  k_comb<<<dim3(64, 4), 256, 0, stream>>>(part, mpart, lpart, feat, alpha, out);
}